// Round 3
// baseline (50.678 us; speedup 1.0000x reference)
//
#include <hip/hip_runtime.h>

// Reference reduces to:
//   u  = embed_user[user]            [B,128]
//   it = embed_item[item]            [B,128]
//   predict = sum(u*it,-1)*0.7 + average + user_bias[user] + item_bias[item]
// kmeans() is dead code (cluster_pred = 0.0 constant).
// Output layout (flat f32): predict[B] | u[B*128] | it[B*128].
//
// Layout: 256-thread block = 4 waves; each wave handles 8 rows (two halves
// of 32 lanes x 4 unrolled row-pairs -> 8 gathered 16 B loads in flight per
// thread). float4 loads; NT stores for the streaming outputs.

typedef float f32x4 __attribute__((ext_vector_type(4)));

__global__ __launch_bounds__(256) void cbmf_gather_dot(
    const int* __restrict__ user,
    const int* __restrict__ item,
    const float* __restrict__ average,
    const float* __restrict__ embed_user,
    const float* __restrict__ embed_item,
    const float* __restrict__ user_bias,
    const float* __restrict__ item_bias,
    float* __restrict__ out_pred,
    float* __restrict__ out_u,
    float* __restrict__ out_it,
    int B)
{
    const int wave = threadIdx.x >> 6;      // 0..3
    const int lane = threadIdx.x & 63;
    const int half = lane >> 5;             // 0 or 1: which row of the pair
    const int l32  = lane & 31;             // 32 lanes x 16 B = 512 B row

    const int base = (blockIdx.x << 5) + (wave << 3);  // 32 rows/block, 8/wave
    const int r0 = base + half;
    const int r1 = base + 2 + half;
    const int r2 = base + 4 + half;
    const int r3 = base + 6 + half;
    if (r0 >= B) return;
    const bool h1 = (r1 < B), h2 = (r2 < B), h3 = (r3 < B);

    // all indices first so all 8 embedding gathers can be in flight
    const int u0 = user[r0],            i0 = item[r0];
    const int u1 = h1 ? user[r1] : u0,  i1 = h1 ? item[r1] : i0;
    const int u2 = h2 ? user[r2] : u0,  i2 = h2 ? item[r2] : i0;
    const int u3 = h3 ? user[r3] : u0,  i3 = h3 ? item[r3] : i0;

    const f32x4 ua = ((const f32x4*)(embed_user + (size_t)u0 * 128))[l32];
    const f32x4 va = ((const f32x4*)(embed_item + (size_t)i0 * 128))[l32];
    const f32x4 ub = ((const f32x4*)(embed_user + (size_t)u1 * 128))[l32];
    const f32x4 vb = ((const f32x4*)(embed_item + (size_t)i1 * 128))[l32];
    const f32x4 uc = ((const f32x4*)(embed_user + (size_t)u2 * 128))[l32];
    const f32x4 vc = ((const f32x4*)(embed_item + (size_t)i2 * 128))[l32];
    const f32x4 ud = ((const f32x4*)(embed_user + (size_t)u3 * 128))[l32];
    const f32x4 vd = ((const f32x4*)(embed_item + (size_t)i3 * 128))[l32];

    // streaming outputs -> nontemporal (no reuse; keep L2/L3 for gathers)
    __builtin_nontemporal_store(ua, ((f32x4*)(out_u  + (size_t)r0 * 128)) + l32);
    __builtin_nontemporal_store(va, ((f32x4*)(out_it + (size_t)r0 * 128)) + l32);
    if (h1) {
        __builtin_nontemporal_store(ub, ((f32x4*)(out_u  + (size_t)r1 * 128)) + l32);
        __builtin_nontemporal_store(vb, ((f32x4*)(out_it + (size_t)r1 * 128)) + l32);
    }
    if (h2) {
        __builtin_nontemporal_store(uc, ((f32x4*)(out_u  + (size_t)r2 * 128)) + l32);
        __builtin_nontemporal_store(vc, ((f32x4*)(out_it + (size_t)r2 * 128)) + l32);
    }
    if (h3) {
        __builtin_nontemporal_store(ud, ((f32x4*)(out_u  + (size_t)r3 * 128)) + l32);
        __builtin_nontemporal_store(vd, ((f32x4*)(out_it + (size_t)r3 * 128)) + l32);
    }

    float dA = ua[0]*va[0] + ua[1]*va[1] + ua[2]*va[2] + ua[3]*va[3];
    float dB = ub[0]*vb[0] + ub[1]*vb[1] + ub[2]*vb[2] + ub[3]*vb[3];
    float dC = uc[0]*vc[0] + uc[1]*vc[1] + uc[2]*vc[2] + uc[3]*vc[3];
    float dD = ud[0]*vd[0] + ud[1]*vd[1] + ud[2]*vd[2] + ud[3]*vd[3];

    #pragma unroll
    for (int off = 16; off > 0; off >>= 1) {
        dA += __shfl_down(dA, off, 32);
        dB += __shfl_down(dB, off, 32);
        dC += __shfl_down(dC, off, 32);
        dD += __shfl_down(dD, off, 32);
    }

    if (l32 == 0) {
        const float avg = average[0];
        out_pred[r0] = dA * 0.7f + avg + user_bias[u0] + item_bias[i0];
        if (h1) out_pred[r1] = dB * 0.7f + avg + user_bias[u1] + item_bias[i1];
        if (h2) out_pred[r2] = dC * 0.7f + avg + user_bias[u2] + item_bias[i2];
        if (h3) out_pred[r3] = dD * 0.7f + avg + user_bias[u3] + item_bias[i3];
    }
}

extern "C" void kernel_launch(void* const* d_in, const int* in_sizes, int n_in,
                              void* d_out, int out_size, void* d_ws, size_t ws_size,
                              hipStream_t stream) {
    const int*   user       = (const int*)d_in[0];
    const int*   item       = (const int*)d_in[1];
    const float* average    = (const float*)d_in[2];
    const float* embed_user = (const float*)d_in[3];
    const float* embed_item = (const float*)d_in[4];
    const float* user_bias  = (const float*)d_in[5];
    const float* item_bias  = (const float*)d_in[6];

    const int B = in_sizes[0];

    float* out_pred = (float*)d_out;
    float* out_u    = out_pred + B;
    float* out_it   = out_u + (size_t)B * 128;

    const int blocks = (B + 31) / 32;  // 32 rows per 256-thread block
    cbmf_gather_dot<<<blocks, 256, 0, stream>>>(
        user, item, average, embed_user, embed_item, user_bias, item_bias,
        out_pred, out_u, out_it, B);
}

// Round 4
// 49.729 us; speedup vs baseline: 1.0191x; 1.0191x over previous
//
#include <hip/hip_runtime.h>

// Reference reduces to:
//   u  = embed_user[user]            [B,128]
//   it = embed_item[item]            [B,128]
//   predict = sum(u*it,-1)*0.7 + average + user_bias[user] + item_bias[item]
// kmeans() is dead code (cluster_pred = 0.0 constant).
// Output layout (flat f32): predict[B] | u[B*128] | it[B*128].
//
// Best measured config (round 2): 256-thread block = 4 waves; each wave
// handles 4 rows (two halves of 32 lanes x 2 unrolled row-pairs).
// 16 B/lane float4 loads; NT stores for streaming outputs.
// Round-3 A/B showed 8 rows/wave is neutral-to-negative -> DRAM-bound.

typedef float f32x4 __attribute__((ext_vector_type(4)));

__global__ __launch_bounds__(256) void cbmf_gather_dot(
    const int* __restrict__ user,
    const int* __restrict__ item,
    const float* __restrict__ average,
    const float* __restrict__ embed_user,
    const float* __restrict__ embed_item,
    const float* __restrict__ user_bias,
    const float* __restrict__ item_bias,
    float* __restrict__ out_pred,
    float* __restrict__ out_u,
    float* __restrict__ out_it,
    int B)
{
    const int wave = threadIdx.x >> 6;      // 0..3
    const int lane = threadIdx.x & 63;
    const int half = lane >> 5;             // 0 or 1: which row of the pair
    const int l32  = lane & 31;             // 32 lanes x 16 B = 512 B row

    const int base = (blockIdx.x << 4) + (wave << 2);  // 16 rows/block
    const int rowA = base + half;
    const int rowB = base + 2 + half;
    if (rowA >= B) return;
    const bool hasB = (rowB < B);

    // indices first (both rows) so all 4 embedding gathers can be in flight
    const int uA = user[rowA];
    const int iA = item[rowA];
    const int uB = hasB ? user[rowB] : uA;
    const int iB = hasB ? item[rowB] : iA;

    const f32x4 ua = ((const f32x4*)(embed_user + (size_t)uA * 128))[l32];
    const f32x4 va = ((const f32x4*)(embed_item + (size_t)iA * 128))[l32];
    const f32x4 ub = ((const f32x4*)(embed_user + (size_t)uB * 128))[l32];
    const f32x4 vb = ((const f32x4*)(embed_item + (size_t)iB * 128))[l32];

    // streaming outputs -> nontemporal (no reuse; keep L2/L3 for gathers)
    __builtin_nontemporal_store(ua, ((f32x4*)(out_u  + (size_t)rowA * 128)) + l32);
    __builtin_nontemporal_store(va, ((f32x4*)(out_it + (size_t)rowA * 128)) + l32);
    if (hasB) {
        __builtin_nontemporal_store(ub, ((f32x4*)(out_u  + (size_t)rowB * 128)) + l32);
        __builtin_nontemporal_store(vb, ((f32x4*)(out_it + (size_t)rowB * 128)) + l32);
    }

    float dotA = ua[0]*va[0] + ua[1]*va[1] + ua[2]*va[2] + ua[3]*va[3];
    float dotB = ub[0]*vb[0] + ub[1]*vb[1] + ub[2]*vb[2] + ub[3]*vb[3];

    #pragma unroll
    for (int off = 16; off > 0; off >>= 1) {
        dotA += __shfl_down(dotA, off, 32);
        dotB += __shfl_down(dotB, off, 32);
    }

    if (l32 == 0) {
        const float avg = average[0];
        out_pred[rowA] = dotA * 0.7f + avg + user_bias[uA] + item_bias[iA];
        if (hasB)
            out_pred[rowB] = dotB * 0.7f + avg + user_bias[uB] + item_bias[iB];
    }
}

extern "C" void kernel_launch(void* const* d_in, const int* in_sizes, int n_in,
                              void* d_out, int out_size, void* d_ws, size_t ws_size,
                              hipStream_t stream) {
    const int*   user       = (const int*)d_in[0];
    const int*   item       = (const int*)d_in[1];
    const float* average    = (const float*)d_in[2];
    const float* embed_user = (const float*)d_in[3];
    const float* embed_item = (const float*)d_in[4];
    const float* user_bias  = (const float*)d_in[5];
    const float* item_bias  = (const float*)d_in[6];

    const int B = in_sizes[0];

    float* out_pred = (float*)d_out;
    float* out_u    = out_pred + B;
    float* out_it   = out_u + (size_t)B * 128;

    const int blocks = (B + 15) / 16;  // 16 rows per 256-thread block
    cbmf_gather_dot<<<blocks, 256, 0, stream>>>(
        user, item, average, embed_user, embed_item, user_bias, item_bias,
        out_pred, out_u, out_it, B);
}